// Round 5
// baseline (528.459 us; speedup 1.0000x reference)
//
#include <hip/hip_runtime.h>
#include <hip/hip_bf16.h>

typedef __attribute__((ext_vector_type(8))) short bf16x8;
typedef __attribute__((ext_vector_type(4))) float f32x4;

#define NB 16384
#define NE 31
#define KS_GRID 1024
#define KS_ITEMS (NB / KS_GRID)   // 16 items per persistent block

static __device__ __forceinline__ unsigned short f2b(float f) {
  unsigned int u = __builtin_bit_cast(unsigned int, f);
  return (unsigned short)((u + 0x7fffu + ((u >> 16) & 1u)) >> 16);
}
static __device__ __forceinline__ float b2f(unsigned short h) {
  return __builtin_bit_cast(float, ((unsigned int)h) << 16);
}

// ---------------------------------------------------------------------------
// k0_all: all weight preprocessing in one launch.
// W1 (bf16 [1792][256]): rows 0..255 = 0.125*Wq; 256..511 = Wk; 512..767 = Wv;
//   rows 768..1791 = Wqo[h*256+c][k] = sum_d 0.125*Wq[h*64+d][k]*Wok[h*64+d][c]
// W2 (bf16 [256][1280]): row n: cols h*256+c = sum_d Wov[h*64+d][c]*Wc[n][h*64+d];
//   cols 1024+m = Wc[n][m]
// ---------------------------------------------------------------------------
__global__ void k0_all(const float* __restrict__ wq, const float* __restrict__ wk,
                       const float* __restrict__ wv, const float* __restrict__ wok,
                       const float* __restrict__ wov, const float* __restrict__ wc,
                       unsigned short* __restrict__ W1, unsigned short* __restrict__ W2) {
  int r = blockIdx.x, k = threadIdx.x;
  if (r < 1024) {
    if (r < 256) {
      W1[r * 256 + k] = f2b(0.125f * wq[r * 256 + k]);
    } else if (r < 512) {
      W1[r * 256 + k] = f2b(wk[(r - 256) * 256 + k]);
    } else if (r < 768) {
      W1[r * 256 + k] = f2b(wv[(r - 512) * 256 + k]);
    } else {
      int n = r - 768;
      W2[n * 1280 + 1024 + k] = f2b(wc[n * 256 + k]);
    }
  } else if (r < 2048) {
    int m = r - 1024;  // 0..1023
    int h = m >> 8, c = m & 255;
    float acc = 0.f;
#pragma unroll 8
    for (int d = 0; d < 64; ++d)
      acc = fmaf(wq[(h * 64 + d) * 256 + k], wok[(h * 64 + d) * 256 + c], acc);
    W1[(768 + m) * 256 + k] = f2b(0.125f * acc);
  } else {
    int n = r - 2048;  // 0..255
#pragma unroll 1
    for (int mi = 0; mi < 4; ++mi) {
      float acc = 0.f;
#pragma unroll 8
      for (int d = 0; d < 64; ++d)
        acc = fmaf(wov[(mi * 64 + d) * 256 + k], wc[n * 256 + mi * 64 + d], acc);
      W2[n * 1280 + mi * 256 + k] = f2b(acc);
    }
  }
}

// ---------------------------------------------------------------------------
// k1b: qkv2[b][n] = sum_k ego[b][k] * W1[n][k], n in [0,1792). bf16 out.
// 256 blocks x 64 rows; 4 waves, each a 448-col stripe (round-2 shape).
// ---------------------------------------------------------------------------
__global__ __launch_bounds__(256, 2)
void k1b(const float* __restrict__ ego, const unsigned short* __restrict__ W1,
         unsigned short* __restrict__ qkv2) {
  __shared__ __align__(16) unsigned short Al[64 * 256];  // 32KB, swizzled
  const int tid = threadIdx.x;
  const int bM = blockIdx.x * 64;
#pragma unroll
  for (int it = 0; it < 8; ++it) {
    int c = tid + it * 256;                // 2048 chunks of 8 f32
    int row = c >> 5, k8 = c & 31;
    const float4* g = (const float4*)(ego + (size_t)(bM + row) * 256 + k8 * 8);
    float4 x = g[0], y = g[1];
    float t[8] = {x.x, x.y, x.z, x.w, y.x, y.y, y.z, y.w};
    bf16x8 v;
#pragma unroll
    for (int j = 0; j < 8; ++j) v[j] = (short)f2b(t[j]);
    int byteoff = row * 512 + ((k8 * 16) ^ ((row & 7) << 4));
    *(bf16x8*)((char*)Al + byteoff) = v;
  }
  __syncthreads();
  const int w = tid >> 6, lane = tid & 63, lr = lane & 15, lkg = lane >> 4;
#pragma unroll 1
  for (int cb = 0; cb < 7; ++cb) {
    int bN = w * 448 + cb * 64;
    f32x4 acc[4][4];
#pragma unroll
    for (int mt = 0; mt < 4; ++mt)
#pragma unroll
      for (int nt = 0; nt < 4; ++nt) acc[mt][nt] = (f32x4){0.f, 0.f, 0.f, 0.f};
#pragma unroll
    for (int kk = 0; kk < 8; ++kk) {
      int kidx = kk * 32 + lkg * 8;
      bf16x8 bfr[4];
#pragma unroll
      for (int nt = 0; nt < 4; ++nt)
        bfr[nt] = *(const bf16x8*)(W1 + (size_t)(bN + nt * 16 + lr) * 256 + kidx);
#pragma unroll
      for (int mt = 0; mt < 4; ++mt) {
        int row = mt * 16 + lr;
        int byteoff = row * 512 + ((kidx * 2) ^ ((row & 7) << 4));
        bf16x8 a = *(const bf16x8*)((const char*)Al + byteoff);
#pragma unroll
        for (int nt = 0; nt < 4; ++nt)
          acc[mt][nt] = __builtin_amdgcn_mfma_f32_16x16x32_bf16(a, bfr[nt], acc[mt][nt], 0, 0, 0);
      }
    }
#pragma unroll
    for (int mt = 0; mt < 4; ++mt)
#pragma unroll
      for (int nt = 0; nt < 4; ++nt)
#pragma unroll
        for (int j = 0; j < 4; ++j) {
          int row = bM + mt * 16 + lkg * 4 + j;
          int col = bN + nt * 16 + lr;
          qkv2[(size_t)row * 1792 + col] = f2b(acc[mt][nt][j]);
        }
  }
}

// ---------------------------------------------------------------------------
// ks_attn: persistent, async-pipelined. Each block handles KS_ITEMS consecutive
// items. Per iteration: commit regs->LDS for item i, issue global loads for
// item i+1 (stay in flight across RAW s_barrier - no vmcnt drain), compute.
// ---------------------------------------------------------------------------
__global__ __launch_bounds__(256, 4)
void ks_attn(const float* __restrict__ others, const int* __restrict__ mask,
             const unsigned short* __restrict__ qkv2,
             unsigned short* __restrict__ u,
             float* __restrict__ attnout) {
  __shared__ __align__(16) unsigned short Xr[32 * 264];   // 16.5KB, stride 264
  __shared__ __align__(16) unsigned short Qo_l[1024];     // 4 heads x 256
  __shared__ __align__(16) unsigned short qk_l[768];      // q,k,v ego (q pre-scaled)
  __shared__ int maskl[32];
  __shared__ float sco_l[4][32];
  __shared__ float Pl[4][32];
  const int tid = threadIdx.x;
  const int w = tid >> 6, lane = tid & 63, lr = lane & 15, lkg = lane >> 4;
  const int e = tid >> 3, c = tid & 7;   // staging role: 8 threads per entity row
  const size_t b0 = (size_t)blockIdx.x * KS_ITEMS;

  float4 f[8];    // in-flight others rows (128B/thread)
  bf16x8 qv;      // in-flight qkv2 chunk
  int4 mv;        // in-flight mask chunk (threads 248..255)

  auto issue = [&](size_t bb) {
    if (e < 31) {
      const float4* src = (const float4*)(others) + ((bb * 31 + e) * 64 + c * 8);
#pragma unroll
      for (int j = 0; j < 8; ++j) f[j] = src[j];
    }
    if (tid < 224) qv = *(const bf16x8*)(qkv2 + bb * 1792 + tid * 8);
    if (tid >= 248) mv = *(const int4*)(mask + bb * 32 + (tid - 248) * 4);
  };
  auto commit = [&]() {
    if (e < 31) {
#pragma unroll
      for (int j = 0; j < 4; ++j) {
        bf16x8 v;
        v[0] = (short)f2b(f[2 * j].x);     v[1] = (short)f2b(f[2 * j].y);
        v[2] = (short)f2b(f[2 * j].z);     v[3] = (short)f2b(f[2 * j].w);
        v[4] = (short)f2b(f[2 * j + 1].x); v[5] = (short)f2b(f[2 * j + 1].y);
        v[6] = (short)f2b(f[2 * j + 1].z); v[7] = (short)f2b(f[2 * j + 1].w);
        *(bf16x8*)(&Xr[e * 264 + c * 32 + j * 8]) = v;
      }
    } else {
      bf16x8 z = (bf16x8){0, 0, 0, 0, 0, 0, 0, 0};
#pragma unroll
      for (int j = 0; j < 4; ++j) *(bf16x8*)(&Xr[31 * 264 + c * 32 + j * 8]) = z;
      *(int4*)(&maskl[(tid - 248) * 4]) = mv;
    }
    if (tid < 224) {
      if (tid < 96) *(bf16x8*)(&qk_l[tid * 8]) = qv;
      else          *(bf16x8*)(&Qo_l[(tid - 96) * 8]) = qv;
    }
  };

  issue(b0);
#pragma unroll 1
  for (int it = 0; it < KS_ITEMS; ++it) {
    const size_t bb = b0 + it;
    commit();                                  // waits on in-flight regs only
    if (it + 1 < KS_ITEMS) issue(bb + 1);      // next item's loads -> in flight
    asm volatile("s_waitcnt lgkmcnt(0)" ::: "memory");
    __builtin_amdgcn_s_barrier();              // NO vmcnt drain

    // ---- scores ----
    if (w < 2) {
      // S[m][n] = Qo[m] . x_n ; wave w covers entities n = w*16 .. w*16+15
      f32x4 acc = (f32x4){0.f, 0.f, 0.f, 0.f};
#pragma unroll
      for (int kk = 0; kk < 8; ++kk) {
        bf16x8 a = *(const bf16x8*)(&Qo_l[(lr & 3) * 256 + kk * 32 + lkg * 8]);
        bf16x8 bbf = *(const bf16x8*)(&Xr[(w * 16 + lr) * 264 + kk * 32 + lkg * 8]);
        acc = __builtin_amdgcn_mfma_f32_16x16x32_bf16(a, bbf, acc, 0, 0, 0);
      }
      if (lkg == 0) {
        int n = w * 16 + lr;
        if (n < NE) {
#pragma unroll
          for (int j = 0; j < 4; ++j) sco_l[j][1 + n] = acc[j];
        }
      }
    } else if (w == 2) {
      // s0[h] = q_h . k_ego_h (q pre-scaled)
      int h = lane >> 4, i = lane & 15;
      const unsigned short* q4 = &qk_l[h * 64 + i * 4];
      const unsigned short* k4p = &qk_l[256 + h * 64 + i * 4];
      float s = 0.f;
#pragma unroll
      for (int j = 0; j < 4; ++j) s += b2f(q4[j]) * b2f(k4p[j]);
#pragma unroll
      for (int off = 1; off < 16; off <<= 1) s += __shfl_xor(s, off, 16);
      if (i == 0) sco_l[h][0] = s;
    }
    asm volatile("s_waitcnt lgkmcnt(0)" ::: "memory");
    __builtin_amdgcn_s_barrier();              // scores visible; vmcnt survives

    // ---- masked softmax: wave w = head w (lanes 32..63 duplicate) ----
    {
      int key = lane & 31;
      float s = sco_l[w][key];
      if (maskl[key] != 0) s = -1e9f;
      float mx = s;
#pragma unroll
      for (int off = 1; off < 32; off <<= 1) mx = fmaxf(mx, __shfl_xor(mx, off, 32));
      float ex = __expf(s - mx);
      float sm = ex;
#pragma unroll
      for (int off = 1; off < 32; off <<= 1) sm += __shfl_xor(sm, off, 32);
      float p = ex / sm;
      if (lane < 32) {
        Pl[w][key] = p;
        attnout[bb * 128 + w * 32 + key] = p;
      }
    }
    // (no barrier: wave w only consumes Pl[w], which it wrote itself)

    // ---- ctx_h = sum_e p_e x_e ; u = [ctx ; p0*v_ego] ----
    {
      float a0 = 0.f, a1 = 0.f, a2 = 0.f, a3 = 0.f;
#pragma unroll
      for (int ee = 0; ee < NE; ++ee) {
        float p = Pl[w][1 + ee];
        ushort4 xv = *(const ushort4*)(&Xr[ee * 264 + lane * 4]);
        a0 = fmaf(p, b2f(xv.x), a0);
        a1 = fmaf(p, b2f(xv.y), a1);
        a2 = fmaf(p, b2f(xv.z), a2);
        a3 = fmaf(p, b2f(xv.w), a3);
      }
      ushort4 st;
      st.x = f2b(a0); st.y = f2b(a1); st.z = f2b(a2); st.w = f2b(a3);
      *(ushort4*)(u + bb * 1280 + w * 256 + lane * 4) = st;
      float p0 = Pl[w][0];
      u[bb * 1280 + 1024 + w * 64 + lane] = f2b(p0 * b2f(qk_l[512 + w * 64 + lane]));
    }
    // all waves done reading Xr/qk_l before next commit overwrites
    asm volatile("" ::: "memory");
    __builtin_amdgcn_s_barrier();
    asm volatile("" ::: "memory");
  }
}

// ---------------------------------------------------------------------------
// k4: res[b][n] = (sum_m u[b][m]*W2[n][m] + ego[b][n]) * 0.5
// 512 blocks x 32 rows; K looped in 5 chunks of 256; 4 waves = 64-col stripes.
// ---------------------------------------------------------------------------
__global__ __launch_bounds__(256, 2)
void k4_out(const unsigned short* __restrict__ u, const unsigned short* __restrict__ W2,
            const float* __restrict__ ego, float* __restrict__ out) {
  __shared__ __align__(16) unsigned short Au[32 * 256];  // 16KB, swizzled
  const int tid = threadIdx.x;
  const int bM = blockIdx.x * 32;
  const int w = tid >> 6, lane = tid & 63, lr = lane & 15, lkg = lane >> 4;
  f32x4 acc[2][4];
#pragma unroll
  for (int mt = 0; mt < 2; ++mt)
#pragma unroll
    for (int nt = 0; nt < 4; ++nt) acc[mt][nt] = (f32x4){0.f, 0.f, 0.f, 0.f};
#pragma unroll 1
  for (int kc = 0; kc < 5; ++kc) {
#pragma unroll
    for (int it = 0; it < 4; ++it) {
      int c = tid + it * 256;              // 1024 chunks of 8 bf16
      int row = c >> 5, k8 = c & 31;
      bf16x8 v = *(const bf16x8*)(u + (size_t)(bM + row) * 1280 + kc * 256 + k8 * 8);
      int byteoff = row * 512 + ((k8 * 16) ^ ((row & 7) << 4));
      *(bf16x8*)((char*)Au + byteoff) = v;
    }
    __syncthreads();
#pragma unroll
    for (int kk = 0; kk < 8; ++kk) {
      int kidx = kk * 32 + lkg * 8;
      bf16x8 bfr[4];
#pragma unroll
      for (int nt = 0; nt < 4; ++nt)
        bfr[nt] = *(const bf16x8*)(W2 + (size_t)(w * 64 + nt * 16 + lr) * 1280 + kc * 256 + kidx);
#pragma unroll
      for (int mt = 0; mt < 2; ++mt) {
        int row = mt * 16 + lr;
        int byteoff = row * 512 + ((kidx * 2) ^ ((row & 7) << 4));
        bf16x8 a = *(const bf16x8*)((const char*)Au + byteoff);
#pragma unroll
        for (int nt = 0; nt < 4; ++nt)
          acc[mt][nt] = __builtin_amdgcn_mfma_f32_16x16x32_bf16(a, bfr[nt], acc[mt][nt], 0, 0, 0);
      }
    }
    __syncthreads();
  }
#pragma unroll
  for (int mt = 0; mt < 2; ++mt)
#pragma unroll
    for (int nt = 0; nt < 4; ++nt)
#pragma unroll
      for (int j = 0; j < 4; ++j) {
        int row = bM + mt * 16 + lkg * 4 + j;
        int col = w * 64 + nt * 16 + lr;
        out[(size_t)row * 256 + col] = (acc[mt][nt][j] + ego[(size_t)row * 256 + col]) * 0.5f;
      }
}

extern "C" void kernel_launch(void* const* d_in, const int* in_sizes, int n_in,
                              void* d_out, int out_size, void* d_ws, size_t ws_size,
                              hipStream_t stream) {
  const float* ego    = (const float*)d_in[0];
  const float* others = (const float*)d_in[1];
  const int*   mask   = (const int*)d_in[2];
  const float* wq  = (const float*)d_in[3];
  const float* wk  = (const float*)d_in[4];
  const float* wv  = (const float*)d_in[5];
  const float* wok = (const float*)d_in[6];
  const float* wov = (const float*)d_in[7];
  const float* wc  = (const float*)d_in[8];

  unsigned short* W1   = (unsigned short*)d_ws;                 // 1792*256
  unsigned short* W2   = W1 + 1792 * 256;                       // 256*1280
  unsigned short* qkv2 = W2 + 256 * 1280;                       // NB*1792
  unsigned short* u    = qkv2 + (size_t)NB * 1792;              // NB*1280

  float* res  = (float*)d_out;                                  // NB*256 f32
  float* attn = res + (size_t)NB * 256;                         // NB*128 f32

  hipLaunchKernelGGL(k0_all, dim3(2304), dim3(256), 0, stream,
                     wq, wk, wv, wok, wov, wc, W1, W2);
  hipLaunchKernelGGL(k1b,    dim3(256),  dim3(256), 0, stream, ego, W1, qkv2);
  hipLaunchKernelGGL(ks_attn, dim3(KS_GRID), dim3(256), 0, stream,
                     others, mask, qkv2, u, attn);
  hipLaunchKernelGGL(k4_out, dim3(512),  dim3(256), 0, stream, u, W2, ego, res);
}

// Round 6
// 280.966 us; speedup vs baseline: 1.8809x; 1.8809x over previous
//
#include <hip/hip_runtime.h>
#include <hip/hip_bf16.h>

typedef __attribute__((ext_vector_type(8))) short bf16x8;
typedef __attribute__((ext_vector_type(4))) float f32x4;

#define NB 16384
#define NE 31
#define KS_ITEMS 32
#define KS_GRID (NB / KS_ITEMS)   // 512 blocks, 2 per CU

static __device__ __forceinline__ unsigned short f2b(float f) {
  unsigned int u = __builtin_bit_cast(unsigned int, f);
  return (unsigned short)((u + 0x7fffu + ((u >> 16) & 1u)) >> 16);
}
static __device__ __forceinline__ float b2f(unsigned short h) {
  return __builtin_bit_cast(float, ((unsigned int)h) << 16);
}
static __device__ __forceinline__ void gload16(const void* g, void* l) {
  __builtin_amdgcn_global_load_lds(
      (const __attribute__((address_space(1))) void*)g,
      (__attribute__((address_space(3))) void*)l, 16, 0, 0);
}

// ---------------------------------------------------------------------------
// k0_all: weight preprocessing (one launch).
// W1 (bf16 [1792][256]): rows 0..255 = 0.125*Wq; 256..511 = Wk; 512..767 = Wv;
//   rows 768..1791 = Wqo[h*256+c][k] = sum_d 0.125*Wq[h*64+d][k]*Wok[h*64+d][c]
// W2 (bf16 [256][1280]): row n: cols h*256+c = sum_d Wov[h*64+d][c]*Wc[n][h*64+d];
//   cols 1024+m = Wc[n][m]
// ---------------------------------------------------------------------------
__global__ void k0_all(const float* __restrict__ wq, const float* __restrict__ wk,
                       const float* __restrict__ wv, const float* __restrict__ wok,
                       const float* __restrict__ wov, const float* __restrict__ wc,
                       unsigned short* __restrict__ W1, unsigned short* __restrict__ W2) {
  int r = blockIdx.x, k = threadIdx.x;
  if (r < 1024) {
    if (r < 256) {
      W1[r * 256 + k] = f2b(0.125f * wq[r * 256 + k]);
    } else if (r < 512) {
      W1[r * 256 + k] = f2b(wk[(r - 256) * 256 + k]);
    } else if (r < 768) {
      W1[r * 256 + k] = f2b(wv[(r - 512) * 256 + k]);
    } else {
      int n = r - 768;
      W2[n * 1280 + 1024 + k] = f2b(wc[n * 256 + k]);
    }
  } else if (r < 2048) {
    int m = r - 1024;  // 0..1023
    int h = m >> 8, c = m & 255;
    float acc = 0.f;
#pragma unroll 8
    for (int d = 0; d < 64; ++d)
      acc = fmaf(wq[(h * 64 + d) * 256 + k], wok[(h * 64 + d) * 256 + c], acc);
    W1[(768 + m) * 256 + k] = f2b(0.125f * acc);
  } else {
    int n = r - 2048;  // 0..255
#pragma unroll 1
    for (int mi = 0; mi < 4; ++mi) {
      float acc = 0.f;
#pragma unroll 8
      for (int d = 0; d < 64; ++d)
        acc = fmaf(wov[(mi * 64 + d) * 256 + k], wc[n * 256 + mi * 64 + d], acc);
      W2[n * 1280 + mi * 256 + k] = f2b(acc);
    }
  }
}

// ---------------------------------------------------------------------------
// k1b: qkv2[b][n] = sum_k ego[b][k] * W1[n][k], n in [0,1792). bf16 out.
// 256 blocks x 64 rows; 4 waves, each a 448-col stripe (round-2 shape).
// ---------------------------------------------------------------------------
__global__ __launch_bounds__(256, 2)
void k1b(const float* __restrict__ ego, const unsigned short* __restrict__ W1,
         unsigned short* __restrict__ qkv2) {
  __shared__ __align__(16) unsigned short Al[64 * 256];  // 32KB, swizzled
  const int tid = threadIdx.x;
  const int bM = blockIdx.x * 64;
#pragma unroll
  for (int it = 0; it < 8; ++it) {
    int c = tid + it * 256;                // 2048 chunks of 8 f32
    int row = c >> 5, k8 = c & 31;
    const float4* g = (const float4*)(ego + (size_t)(bM + row) * 256 + k8 * 8);
    float4 x = g[0], y = g[1];
    float t[8] = {x.x, x.y, x.z, x.w, y.x, y.y, y.z, y.w};
    bf16x8 v;
#pragma unroll
    for (int j = 0; j < 8; ++j) v[j] = (short)f2b(t[j]);
    int byteoff = row * 512 + ((k8 * 16) ^ ((row & 7) << 4));
    *(bf16x8*)((char*)Al + byteoff) = v;
  }
  __syncthreads();
  const int w = tid >> 6, lane = tid & 63, lr = lane & 15, lkg = lane >> 4;
#pragma unroll 1
  for (int cb = 0; cb < 7; ++cb) {
    int bN = w * 448 + cb * 64;
    f32x4 acc[4][4];
#pragma unroll
    for (int mt = 0; mt < 4; ++mt)
#pragma unroll
      for (int nt = 0; nt < 4; ++nt) acc[mt][nt] = (f32x4){0.f, 0.f, 0.f, 0.f};
#pragma unroll
    for (int kk = 0; kk < 8; ++kk) {
      int kidx = kk * 32 + lkg * 8;
      bf16x8 bfr[4];
#pragma unroll
      for (int nt = 0; nt < 4; ++nt)
        bfr[nt] = *(const bf16x8*)(W1 + (size_t)(bN + nt * 16 + lr) * 256 + kidx);
#pragma unroll
      for (int mt = 0; mt < 4; ++mt) {
        int row = mt * 16 + lr;
        int byteoff = row * 512 + ((kidx * 2) ^ ((row & 7) << 4));
        bf16x8 a = *(const bf16x8*)((const char*)Al + byteoff);
#pragma unroll
        for (int nt = 0; nt < 4; ++nt)
          acc[mt][nt] = __builtin_amdgcn_mfma_f32_16x16x32_bf16(a, bfr[nt], acc[mt][nt], 0, 0, 0);
      }
    }
#pragma unroll
    for (int mt = 0; mt < 4; ++mt)
#pragma unroll
      for (int nt = 0; nt < 4; ++nt)
#pragma unroll
        for (int j = 0; j < 4; ++j) {
          int row = bM + mt * 16 + lkg * 4 + j;
          int col = bN + nt * 16 + lr;
          qkv2[(size_t)row * 1792 + col] = f2b(acc[mt][nt][j]);
        }
  }
}

// ---------------------------------------------------------------------------
// ks_attn: persistent 2-phase pipeline with global_load_lds staging (zero-VGPR).
// X kept in f32 in LDS (double-buffered), source-side XOR swizzle for the
// row-stride bank conflicts. Per iter: issue i+1 -> compute i -> vmcnt(0)+bar.
// ---------------------------------------------------------------------------
__global__ __launch_bounds__(256, 2)
void ks_attn(const float* __restrict__ others, const int* __restrict__ mask,
             const unsigned short* __restrict__ qkv2,
             unsigned short* __restrict__ u,
             float* __restrict__ attnout) {
  __shared__ __align__(16) float Xf[2][32 * 256];        // 2 x 32KB (row 31 unused)
  __shared__ __align__(16) unsigned short Qb[2][2048];   // 2 x 4KB (1792 used)
  __shared__ float sco_l[4][32];
  __shared__ float Pl[4][32];
  const int tid = threadIdx.x;
  const int w = tid >> 6, lane = tid & 63, lr = lane & 15, lkg = lane >> 4;
  const size_t b0 = (size_t)blockIdx.x * KS_ITEMS;

  // issue all staging loads for item bb into buffer `buf` (wave-cooperative,
  // no VGPR round-trip). Tasks 0..30 = others rows (swizzled source),
  // tasks 31..34 = qkv2 row chunks (linear; chunk 3 over-reads 512B, safe).
  auto issue = [&](int buf, size_t bb) {
#pragma unroll 1
    for (int t = w; t < 35; t += 4) {
      if (t < 31) {
        const char* g = (const char*)(others + (bb * 31 + t) * 256) +
                        ((lane * 16) ^ ((t & 7) << 4));
        gload16(g, (char*)&Xf[buf][t * 256]);
      } else {
        int t2 = t - 31;
        const char* g = (const char*)(qkv2 + bb * 1792 + t2 * 512) + lane * 16;
        gload16(g, (char*)&Qb[buf][t2 * 512]);
      }
    }
  };

  issue(0, b0);
  asm volatile("s_waitcnt vmcnt(0)" ::: "memory");
  __builtin_amdgcn_s_barrier();
  __builtin_amdgcn_sched_barrier(0);

#pragma unroll 1
  for (int it = 0; it < KS_ITEMS; ++it) {
    const size_t bb = b0 + it;
    const int cur = it & 1;
    if (it + 1 < KS_ITEMS) issue(cur ^ 1, bb + 1);   // stays in flight

    const float* X = Xf[cur];
    const unsigned short* Q = Qb[cur];

    // ---- scores ----
    if (w < 2) {
      // S[m][n] = Qo[m&3] . x_n ; wave w covers entities n = w*16 .. w*16+15
      f32x4 acc = (f32x4){0.f, 0.f, 0.f, 0.f};
      const int r = w * 16 + lr;
      const int sw = (r & 7) << 4;
      const char* xrow = (const char*)X + r * 1024;
#pragma unroll
      for (int kk = 0; kk < 8; ++kk) {
        bf16x8 a = *(const bf16x8*)(&Q[768 + (lr & 3) * 256 + kk * 32 + lkg * 8]);
        int cb = kk * 128 + lkg * 32;
        float4 x0 = *(const float4*)(xrow + (cb ^ sw));
        float4 x1 = *(const float4*)(xrow + ((cb + 16) ^ sw));
        bf16x8 bfr;
        bfr[0] = (short)f2b(x0.x); bfr[1] = (short)f2b(x0.y);
        bfr[2] = (short)f2b(x0.z); bfr[3] = (short)f2b(x0.w);
        bfr[4] = (short)f2b(x1.x); bfr[5] = (short)f2b(x1.y);
        bfr[6] = (short)f2b(x1.z); bfr[7] = (short)f2b(x1.w);
        acc = __builtin_amdgcn_mfma_f32_16x16x32_bf16(a, bfr, acc, 0, 0, 0);
      }
      if (lkg == 0) {
        int n = w * 16 + lr;
        if (n < NE) {
#pragma unroll
          for (int j = 0; j < 4; ++j) sco_l[j][1 + n] = acc[j];
        }
      }
    } else if (w == 2) {
      // s0[h] = q_h . k_ego_h (q pre-scaled)
      int h = lane >> 4, i = lane & 15;
      float s = 0.f;
#pragma unroll
      for (int j = 0; j < 4; ++j)
        s += b2f(Q[h * 64 + i * 4 + j]) * b2f(Q[256 + h * 64 + i * 4 + j]);
#pragma unroll
      for (int off = 1; off < 16; off <<= 1) s += __shfl_xor(s, off, 16);
      if (i == 0) sco_l[h][0] = s;
    }
    asm volatile("s_waitcnt lgkmcnt(0)" ::: "memory");
    __builtin_amdgcn_s_barrier();              // raw: vmcnt survives
    __builtin_amdgcn_sched_barrier(0);

    // ---- masked softmax: wave w = head w (lanes 32..63 duplicate) ----
    {
      int key = lane & 31;
      float s = sco_l[w][key];
      if (mask[bb * 32 + key] != 0) s = -1e9f;
      float mx = s;
#pragma unroll
      for (int off = 1; off < 32; off <<= 1) mx = fmaxf(mx, __shfl_xor(mx, off, 32));
      float ex = __expf(s - mx);
      float sm = ex;
#pragma unroll
      for (int off = 1; off < 32; off <<= 1) sm += __shfl_xor(sm, off, 32);
      float p = ex / sm;
      if (lane < 32) {
        Pl[w][key] = p;
        attnout[bb * 128 + w * 32 + key] = p;
      }
    }
    // (no barrier: wave w only consumes Pl[w], which it wrote itself)

    // ---- ctx_h = sum_e p_e x_e (f32 direct) ; u = [ctx ; p0*v_ego] ----
    {
      float a0 = 0.f, a1 = 0.f, a2 = 0.f, a3 = 0.f;
#pragma unroll
      for (int e = 0; e < NE; ++e) {
        float p = Pl[w][1 + e];
        float4 xv = *(const float4*)((const char*)X + e * 1024 +
                                     ((lane * 16) ^ ((e & 7) << 4)));
        a0 = fmaf(p, xv.x, a0);
        a1 = fmaf(p, xv.y, a1);
        a2 = fmaf(p, xv.z, a2);
        a3 = fmaf(p, xv.w, a3);
      }
      ushort4 st;
      st.x = f2b(a0); st.y = f2b(a1); st.z = f2b(a2); st.w = f2b(a3);
      *(ushort4*)(u + bb * 1280 + w * 256 + lane * 4) = st;
      float p0 = Pl[w][0];
      u[bb * 1280 + 1024 + w * 64 + lane] = f2b(p0 * b2f(Q[512 + w * 64 + lane]));
    }

    // next item's loads landed; all waves done reading this buffer
    asm volatile("s_waitcnt vmcnt(0)" ::: "memory");
    __builtin_amdgcn_s_barrier();
    __builtin_amdgcn_sched_barrier(0);
  }
}

// ---------------------------------------------------------------------------
// k4: res[b][n] = (sum_m u[b][m]*W2[n][m] + ego[b][n]) * 0.5
// 512 blocks x 32 rows; K looped in 5 chunks of 256; 4 waves = 64-col stripes.
// ---------------------------------------------------------------------------
__global__ __launch_bounds__(256, 2)
void k4_out(const unsigned short* __restrict__ u, const unsigned short* __restrict__ W2,
            const float* __restrict__ ego, float* __restrict__ out) {
  __shared__ __align__(16) unsigned short Au[32 * 256];  // 16KB, swizzled
  const int tid = threadIdx.x;
  const int bM = blockIdx.x * 32;
  const int w = tid >> 6, lane = tid & 63, lr = lane & 15, lkg = lane >> 4;
  f32x4 acc[2][4];
#pragma unroll
  for (int mt = 0; mt < 2; ++mt)
#pragma unroll
    for (int nt = 0; nt < 4; ++nt) acc[mt][nt] = (f32x4){0.f, 0.f, 0.f, 0.f};
#pragma unroll 1
  for (int kc = 0; kc < 5; ++kc) {
#pragma unroll
    for (int it = 0; it < 4; ++it) {
      int c = tid + it * 256;              // 1024 chunks of 8 bf16
      int row = c >> 5, k8 = c & 31;
      bf16x8 v = *(const bf16x8*)(u + (size_t)(bM + row) * 1280 + kc * 256 + k8 * 8);
      int byteoff = row * 512 + ((k8 * 16) ^ ((row & 7) << 4));
      *(bf16x8*)((char*)Au + byteoff) = v;
    }
    __syncthreads();
#pragma unroll
    for (int kk = 0; kk < 8; ++kk) {
      int kidx = kk * 32 + lkg * 8;
      bf16x8 bfr[4];
#pragma unroll
      for (int nt = 0; nt < 4; ++nt)
        bfr[nt] = *(const bf16x8*)(W2 + (size_t)(w * 64 + nt * 16 + lr) * 1280 + kc * 256 + kidx);
#pragma unroll
      for (int mt = 0; mt < 2; ++mt) {
        int row = mt * 16 + lr;
        int byteoff = row * 512 + ((kidx * 2) ^ ((row & 7) << 4));
        bf16x8 a = *(const bf16x8*)((const char*)Au + byteoff);
#pragma unroll
        for (int nt = 0; nt < 4; ++nt)
          acc[mt][nt] = __builtin_amdgcn_mfma_f32_16x16x32_bf16(a, bfr[nt], acc[mt][nt], 0, 0, 0);
      }
    }
    __syncthreads();
  }
#pragma unroll
  for (int mt = 0; mt < 2; ++mt)
#pragma unroll
    for (int nt = 0; nt < 4; ++nt)
#pragma unroll
      for (int j = 0; j < 4; ++j) {
        int row = bM + mt * 16 + lkg * 4 + j;
        int col = w * 64 + nt * 16 + lr;
        out[(size_t)row * 256 + col] = (acc[mt][nt][j] + ego[(size_t)row * 256 + col]) * 0.5f;
      }
}

extern "C" void kernel_launch(void* const* d_in, const int* in_sizes, int n_in,
                              void* d_out, int out_size, void* d_ws, size_t ws_size,
                              hipStream_t stream) {
  const float* ego    = (const float*)d_in[0];
  const float* others = (const float*)d_in[1];
  const int*   mask   = (const int*)d_in[2];
  const float* wq  = (const float*)d_in[3];
  const float* wk  = (const float*)d_in[4];
  const float* wv  = (const float*)d_in[5];
  const float* wok = (const float*)d_in[6];
  const float* wov = (const float*)d_in[7];
  const float* wc  = (const float*)d_in[8];

  unsigned short* W1   = (unsigned short*)d_ws;                 // 1792*256
  unsigned short* W2   = W1 + 1792 * 256;                       // 256*1280
  unsigned short* qkv2 = W2 + 256 * 1280;                       // NB*1792
  unsigned short* u    = qkv2 + (size_t)NB * 1792;              // NB*1280

  float* res  = (float*)d_out;                                  // NB*256 f32
  float* attn = res + (size_t)NB * 256;                         // NB*128 f32

  hipLaunchKernelGGL(k0_all, dim3(2304), dim3(256), 0, stream,
                     wq, wk, wv, wok, wov, wc, W1, W2);
  hipLaunchKernelGGL(k1b,    dim3(256),  dim3(256), 0, stream, ego, W1, qkv2);
  hipLaunchKernelGGL(ks_attn, dim3(KS_GRID), dim3(256), 0, stream,
                     others, mask, qkv2, u, attn);
  hipLaunchKernelGGL(k4_out, dim3(512),  dim3(256), 0, stream, u, W2, ego, res);
}

// Round 7
// 254.373 us; speedup vs baseline: 2.0775x; 1.1045x over previous
//
#include <hip/hip_runtime.h>
#include <hip/hip_bf16.h>

typedef __attribute__((ext_vector_type(8))) short bf16x8;
typedef __attribute__((ext_vector_type(4))) float f32x4;

#define NB 16384
#define NE 31

static __device__ __forceinline__ unsigned short f2b(float f) {
  unsigned int u = __builtin_bit_cast(unsigned int, f);
  return (unsigned short)((u + 0x7fffu + ((u >> 16) & 1u)) >> 16);
}
static __device__ __forceinline__ float b2f(unsigned short h) {
  return __builtin_bit_cast(float, ((unsigned int)h) << 16);
}
static __device__ __forceinline__ unsigned int cvtpk(float a, float b) {
  unsigned int r;
  asm("v_cvt_pk_bf16_f32 %0, %1, %2" : "=v"(r) : "v"(a), "v"(b));
  return r;
}

// ---------------------------------------------------------------------------
// k0_all: weight preprocessing (one launch).
// W1 (bf16 [1792][256]): rows 0..255 = 0.125*Wq; 256..511 = Wk; 512..767 = Wv;
//   rows 768..1791 = Wqo[h*256+c][k] = sum_d 0.125*Wq[h*64+d][k]*Wok[h*64+d][c]
// W2 (bf16 [256][1280]): row n: cols h*256+c = sum_d Wov[h*64+d][c]*Wc[n][h*64+d];
//   cols 1024+m = Wc[n][m]
// ---------------------------------------------------------------------------
__global__ void k0_all(const float* __restrict__ wq, const float* __restrict__ wk,
                       const float* __restrict__ wv, const float* __restrict__ wok,
                       const float* __restrict__ wov, const float* __restrict__ wc,
                       unsigned short* __restrict__ W1, unsigned short* __restrict__ W2) {
  int r = blockIdx.x, k = threadIdx.x;
  if (r < 1024) {
    if (r < 256) {
      W1[r * 256 + k] = f2b(0.125f * wq[r * 256 + k]);
    } else if (r < 512) {
      W1[r * 256 + k] = f2b(wk[(r - 256) * 256 + k]);
    } else if (r < 768) {
      W1[r * 256 + k] = f2b(wv[(r - 512) * 256 + k]);
    } else {
      int n = r - 768;
      W2[n * 1280 + 1024 + k] = f2b(wc[n * 256 + k]);
    }
  } else if (r < 2048) {
    int m = r - 1024;  // 0..1023
    int h = m >> 8, c = m & 255;
    float acc = 0.f;
#pragma unroll 8
    for (int d = 0; d < 64; ++d)
      acc = fmaf(wq[(h * 64 + d) * 256 + k], wok[(h * 64 + d) * 256 + c], acc);
    W1[(768 + m) * 256 + k] = f2b(0.125f * acc);
  } else {
    int n = r - 2048;  // 0..255
#pragma unroll 1
    for (int mi = 0; mi < 4; ++mi) {
      float acc = 0.f;
#pragma unroll 8
      for (int d = 0; d < 64; ++d)
        acc = fmaf(wov[(mi * 64 + d) * 256 + k], wc[n * 256 + mi * 64 + d], acc);
      W2[n * 1280 + mi * 256 + k] = f2b(acc);
    }
  }
}

// ---------------------------------------------------------------------------
// k1b: qkv2[b][n] = sum_k ego[b][k] * W1[n][k], n in [0,1792). bf16 out.
// 256 blocks x 64 rows; 4 waves, each a 448-col stripe (round-2 shape).
// ---------------------------------------------------------------------------
__global__ __launch_bounds__(256, 2)
void k1b(const float* __restrict__ ego, const unsigned short* __restrict__ W1,
         unsigned short* __restrict__ qkv2) {
  __shared__ __align__(16) unsigned short Al[64 * 256];  // 32KB, swizzled
  const int tid = threadIdx.x;
  const int bM = blockIdx.x * 64;
#pragma unroll
  for (int it = 0; it < 8; ++it) {
    int c = tid + it * 256;                // 2048 chunks of 8 f32
    int row = c >> 5, k8 = c & 31;
    const float4* g = (const float4*)(ego + (size_t)(bM + row) * 256 + k8 * 8);
    float4 x = g[0], y = g[1];
    float t[8] = {x.x, x.y, x.z, x.w, y.x, y.y, y.z, y.w};
    bf16x8 v;
#pragma unroll
    for (int j = 0; j < 8; ++j) v[j] = (short)f2b(t[j]);
    int byteoff = row * 512 + ((k8 * 16) ^ ((row & 7) << 4));
    *(bf16x8*)((char*)Al + byteoff) = v;
  }
  __syncthreads();
  const int w = tid >> 6, lane = tid & 63, lr = lane & 15, lkg = lane >> 4;
#pragma unroll 1
  for (int cb = 0; cb < 7; ++cb) {
    int bN = w * 448 + cb * 64;
    f32x4 acc[4][4];
#pragma unroll
    for (int mt = 0; mt < 4; ++mt)
#pragma unroll
      for (int nt = 0; nt < 4; ++nt) acc[mt][nt] = (f32x4){0.f, 0.f, 0.f, 0.f};
#pragma unroll
    for (int kk = 0; kk < 8; ++kk) {
      int kidx = kk * 32 + lkg * 8;
      bf16x8 bfr[4];
#pragma unroll
      for (int nt = 0; nt < 4; ++nt)
        bfr[nt] = *(const bf16x8*)(W1 + (size_t)(bN + nt * 16 + lr) * 256 + kidx);
#pragma unroll
      for (int mt = 0; mt < 4; ++mt) {
        int row = mt * 16 + lr;
        int byteoff = row * 512 + ((kidx * 2) ^ ((row & 7) << 4));
        bf16x8 a = *(const bf16x8*)((const char*)Al + byteoff);
#pragma unroll
        for (int nt = 0; nt < 4; ++nt)
          acc[mt][nt] = __builtin_amdgcn_mfma_f32_16x16x32_bf16(a, bfr[nt], acc[mt][nt], 0, 0, 0);
      }
    }
#pragma unroll
    for (int mt = 0; mt < 4; ++mt)
#pragma unroll
      for (int nt = 0; nt < 4; ++nt)
#pragma unroll
        for (int j = 0; j < 4; ++j) {
          int row = bM + mt * 16 + lkg * 4 + j;
          int col = bN + nt * 16 + lr;
          qkv2[(size_t)row * 1792 + col] = f2b(acc[mt][nt][j]);
        }
  }
}

// ---------------------------------------------------------------------------
// ks_attn: ONE WAVE = ONE ITEM, zero barriers. 4 waves/block, private LDS
// slices. Stage X bf16 (swizzled), MFMA scores (A=Qo frags from L2),
// in-wave softmax, VALU ctx. grid = NB/4.
// ---------------------------------------------------------------------------
__global__ __launch_bounds__(256, 2)
void ks_attn(const float* __restrict__ others, const int* __restrict__ mask,
             const unsigned short* __restrict__ qkv2,
             unsigned short* __restrict__ u,
             float* __restrict__ attnout) {
  __shared__ __align__(16) unsigned short Xs[4][8192];  // 16KB per wave
  __shared__ __align__(16) float Ps[4][32][4];          // [key][head] per wave
  const int tid = threadIdx.x;
  const int w = tid >> 6, lane = tid & 63, lr = lane & 15, lkg = lane >> 4;
  const size_t b = (size_t)blockIdx.x * 4 + w;
  char* Xc = (char*)Xs[w];
  float (*P)[4] = Ps[w];
  const unsigned short* qk = qkv2 + b * 1792;

  // ---- preload A-fragments (Qo) + ego q/k/v bits (L2-resident) ----
  bf16x8 af[8];
#pragma unroll
  for (int kk = 0; kk < 8; ++kk)
    af[kk] = *(const bf16x8*)(qk + 768 + (lr & 3) * 256 + kk * 32 + lkg * 8);
  ushort4 qa = *(const ushort4*)(qk + lkg * 64 + lr * 4);
  ushort4 kb = *(const ushort4*)(qk + 256 + lkg * 64 + lr * 4);
  ushort4 ve = *(const ushort4*)(qk + 512 + lane * 4);
  int mk0 = mask[b * 32 + 1 + lr];
  int mk1 = (lr == 15) ? 1 : mask[b * 32 + 17 + lr];
  int mkE = mask[b * 32];

  // ---- stage X: row j, f32-chunk `lane` (coalesced 1KB/inst) ----
  {
    const char* src = (const char*)(others + b * (NE * 256)) + lane * 16;
#pragma unroll
    for (int j = 0; j < 31; ++j) {
      float4 f = *(const float4*)(src + j * 1024);
      uint2 v;
      v.x = cvtpk(f.x, f.y);
      v.y = cvtpk(f.z, f.w);
      *(uint2*)(Xc + j * 512 + ((lane * 8) ^ ((j & 15) << 4))) = v;
    }
    uint2 z; z.x = 0; z.y = 0;
    *(uint2*)(Xc + 31 * 512 + ((lane * 8) ^ ((31 & 15) << 4))) = z;
  }

  // ---- s0[h] = q_h . k_ego_h (q pre-scaled); group lkg computes head lkg ----
  float s0p = b2f(qa.x) * b2f(kb.x) + b2f(qa.y) * b2f(kb.y) +
              b2f(qa.z) * b2f(kb.z) + b2f(qa.w) * b2f(kb.w);
#pragma unroll
  for (int off = 1; off < 16; off <<= 1) s0p += __shfl_xor(s0p, off, 16);
  float s0h[4];
  s0h[0] = __shfl(s0p, 0);
  s0h[1] = __shfl(s0p, 16);
  s0h[2] = __shfl(s0p, 32);
  s0h[3] = __shfl(s0p, 48);

  asm volatile("s_waitcnt lgkmcnt(0)" ::: "memory");
  __builtin_amdgcn_sched_barrier(0);

  // ---- scores: S[h][e] via MFMA; D row m=h (valid on lkg==0), col n=e ----
  f32x4 acc0 = (f32x4){0.f, 0.f, 0.f, 0.f};
  f32x4 acc1 = (f32x4){0.f, 0.f, 0.f, 0.f};
#pragma unroll
  for (int kk = 0; kk < 8; ++kk) {
    int co = kk * 64 + lkg * 16;
    bf16x8 b0 = *(const bf16x8*)(Xc + lr * 512 + (co ^ (lr << 4)));
    bf16x8 b1 = *(const bf16x8*)(Xc + (16 + lr) * 512 + (co ^ (lr << 4)));
    acc0 = __builtin_amdgcn_mfma_f32_16x16x32_bf16(af[kk], b0, acc0, 0, 0, 0);
    acc1 = __builtin_amdgcn_mfma_f32_16x16x32_bf16(af[kk], b1, acc1, 0, 0, 0);
  }

  // ---- masked softmax per head (width-16 shfl groups; lkg==0 valid) ----
  float pr0[4], pr1[4], p0v[4];
#pragma unroll
  for (int j = 0; j < 4; ++j) {
    float sj0 = mk0 ? -1e9f : acc0[j];
    float sj1 = mk1 ? -1e9f : acc1[j];
    float se  = mkE ? -1e9f : s0h[j];
    float mx = fmaxf(se, fmaxf(sj0, sj1));
#pragma unroll
    for (int off = 1; off < 16; off <<= 1) mx = fmaxf(mx, __shfl_xor(mx, off, 16));
    float e0 = __expf(sj0 - mx), e1 = __expf(sj1 - mx), ee = __expf(se - mx);
    float sm = e0 + e1;
#pragma unroll
    for (int off = 1; off < 16; off <<= 1) sm += __shfl_xor(sm, off, 16);
    float rinv = 1.f / (sm + ee);
    pr0[j] = e0 * rinv;
    pr1[j] = e1 * rinv;
    p0v[j] = ee * rinv;
  }
  if (lkg == 0) {
    float4 q0, q1;
    q0.x = pr0[0]; q0.y = pr0[1]; q0.z = pr0[2]; q0.w = pr0[3];
    *(float4*)&P[1 + lr][0] = q0;
    if (lr < 15) {
      q1.x = pr1[0]; q1.y = pr1[1]; q1.z = pr1[2]; q1.w = pr1[3];
      *(float4*)&P[17 + lr][0] = q1;
    }
    if (lr == 0) {
      float4 qe;
      qe.x = p0v[0]; qe.y = p0v[1]; qe.z = p0v[2]; qe.w = p0v[3];
      *(float4*)&P[0][0] = qe;
    }
#pragma unroll
    for (int j = 0; j < 4; ++j) {
      attnout[b * 128 + j * 32 + 1 + lr] = pr0[j];
      if (lr < 15) attnout[b * 128 + j * 32 + 17 + lr] = pr1[j];
      if (lr == 0) attnout[b * 128 + j * 32] = p0v[j];
    }
  }
  asm volatile("s_waitcnt lgkmcnt(0)" ::: "memory");
  __builtin_amdgcn_sched_barrier(0);

  // ---- ctx[h][d] = sum_e P[h][e] X[e][d]; lane owns 4 d-cols ----
  f32x4 cx[4];
#pragma unroll
  for (int h = 0; h < 4; ++h) cx[h] = (f32x4){0.f, 0.f, 0.f, 0.f};
#pragma unroll
  for (int e = 0; e < NE; ++e) {
    float4 p = *(const float4*)&P[1 + e][0];
    ushort4 xv = *(const ushort4*)(Xc + e * 512 + ((lane * 8) ^ ((e & 15) << 4)));
    float x0 = b2f(xv.x), x1 = b2f(xv.y), x2 = b2f(xv.z), x3 = b2f(xv.w);
    cx[0][0] = fmaf(p.x, x0, cx[0][0]); cx[0][1] = fmaf(p.x, x1, cx[0][1]);
    cx[0][2] = fmaf(p.x, x2, cx[0][2]); cx[0][3] = fmaf(p.x, x3, cx[0][3]);
    cx[1][0] = fmaf(p.y, x0, cx[1][0]); cx[1][1] = fmaf(p.y, x1, cx[1][1]);
    cx[1][2] = fmaf(p.y, x2, cx[1][2]); cx[1][3] = fmaf(p.y, x3, cx[1][3]);
    cx[2][0] = fmaf(p.z, x0, cx[2][0]); cx[2][1] = fmaf(p.z, x1, cx[2][1]);
    cx[2][2] = fmaf(p.z, x2, cx[2][2]); cx[2][3] = fmaf(p.z, x3, cx[2][3]);
    cx[3][0] = fmaf(p.w, x0, cx[3][0]); cx[3][1] = fmaf(p.w, x1, cx[3][1]);
    cx[3][2] = fmaf(p.w, x2, cx[3][2]); cx[3][3] = fmaf(p.w, x3, cx[3][3]);
  }
#pragma unroll
  for (int h = 0; h < 4; ++h) {
    ushort4 st;
    st.x = f2b(cx[h][0]); st.y = f2b(cx[h][1]);
    st.z = f2b(cx[h][2]); st.w = f2b(cx[h][3]);
    *(ushort4*)(u + b * 1280 + h * 256 + lane * 4) = st;
  }
  // p0 * v_ego (head = lkg for this lane's 4-col slice)
  float p0h = P[0][lkg];
  ushort4 sv;
  sv.x = f2b(p0h * b2f(ve.x)); sv.y = f2b(p0h * b2f(ve.y));
  sv.z = f2b(p0h * b2f(ve.z)); sv.w = f2b(p0h * b2f(ve.w));
  *(ushort4*)(u + b * 1280 + 1024 + lane * 4) = sv;
}

// ---------------------------------------------------------------------------
// k4: res[b][n] = (sum_m u[b][m]*W2[n][m] + ego[b][n]) * 0.5
// 512 blocks x 32 rows; K looped in 5 chunks of 256; 4 waves = 64-col stripes.
// ---------------------------------------------------------------------------
__global__ __launch_bounds__(256, 2)
void k4_out(const unsigned short* __restrict__ u, const unsigned short* __restrict__ W2,
            const float* __restrict__ ego, float* __restrict__ out) {
  __shared__ __align__(16) unsigned short Au[32 * 256];  // 16KB, swizzled
  const int tid = threadIdx.x;
  const int bM = blockIdx.x * 32;
  const int w = tid >> 6, lane = tid & 63, lr = lane & 15, lkg = lane >> 4;
  f32x4 acc[2][4];
#pragma unroll
  for (int mt = 0; mt < 2; ++mt)
#pragma unroll
    for (int nt = 0; nt < 4; ++nt) acc[mt][nt] = (f32x4){0.f, 0.f, 0.f, 0.f};
#pragma unroll 1
  for (int kc = 0; kc < 5; ++kc) {
#pragma unroll
    for (int it = 0; it < 4; ++it) {
      int c = tid + it * 256;              // 1024 chunks of 8 bf16
      int row = c >> 5, k8 = c & 31;
      bf16x8 v = *(const bf16x8*)(u + (size_t)(bM + row) * 1280 + kc * 256 + k8 * 8);
      int byteoff = row * 512 + ((k8 * 16) ^ ((row & 7) << 4));
      *(bf16x8*)((char*)Au + byteoff) = v;
    }
    __syncthreads();
#pragma unroll
    for (int kk = 0; kk < 8; ++kk) {
      int kidx = kk * 32 + lkg * 8;
      bf16x8 bfr[4];
#pragma unroll
      for (int nt = 0; nt < 4; ++nt)
        bfr[nt] = *(const bf16x8*)(W2 + (size_t)(w * 64 + nt * 16 + lr) * 1280 + kc * 256 + kidx);
#pragma unroll
      for (int mt = 0; mt < 2; ++mt) {
        int row = mt * 16 + lr;
        int byteoff = row * 512 + ((kidx * 2) ^ ((row & 7) << 4));
        bf16x8 a = *(const bf16x8*)((const char*)Au + byteoff);
#pragma unroll
        for (int nt = 0; nt < 4; ++nt)
          acc[mt][nt] = __builtin_amdgcn_mfma_f32_16x16x32_bf16(a, bfr[nt], acc[mt][nt], 0, 0, 0);
      }
    }
    __syncthreads();
  }
#pragma unroll
  for (int mt = 0; mt < 2; ++mt)
#pragma unroll
    for (int nt = 0; nt < 4; ++nt)
#pragma unroll
      for (int j = 0; j < 4; ++j) {
        int row = bM + mt * 16 + lkg * 4 + j;
        int col = w * 64 + nt * 16 + lr;
        out[(size_t)row * 256 + col] = (acc[mt][nt][j] + ego[(size_t)row * 256 + col]) * 0.5f;
      }
}

extern "C" void kernel_launch(void* const* d_in, const int* in_sizes, int n_in,
                              void* d_out, int out_size, void* d_ws, size_t ws_size,
                              hipStream_t stream) {
  const float* ego    = (const float*)d_in[0];
  const float* others = (const float*)d_in[1];
  const int*   mask   = (const int*)d_in[2];
  const float* wq  = (const float*)d_in[3];
  const float* wk  = (const float*)d_in[4];
  const float* wv  = (const float*)d_in[5];
  const float* wok = (const float*)d_in[6];
  const float* wov = (const float*)d_in[7];
  const float* wc  = (const float*)d_in[8];

  unsigned short* W1   = (unsigned short*)d_ws;                 // 1792*256
  unsigned short* W2   = W1 + 1792 * 256;                       // 256*1280
  unsigned short* qkv2 = W2 + 256 * 1280;                       // NB*1792
  unsigned short* u    = qkv2 + (size_t)NB * 1792;              // NB*1280

  float* res  = (float*)d_out;                                  // NB*256 f32
  float* attn = res + (size_t)NB * 256;                         // NB*128 f32

  hipLaunchKernelGGL(k0_all, dim3(2304), dim3(256), 0, stream,
                     wq, wk, wv, wok, wov, wc, W1, W2);
  hipLaunchKernelGGL(k1b,    dim3(256),  dim3(256), 0, stream, ego, W1, qkv2);
  hipLaunchKernelGGL(ks_attn, dim3(NB / 4), dim3(256), 0, stream,
                     others, mask, qkv2, u, attn);
  hipLaunchKernelGGL(k4_out, dim3(512),  dim3(256), 0, stream, u, W2, ego, res);
}

// Round 8
// 227.428 us; speedup vs baseline: 2.3236x; 1.1185x over previous
//
#include <hip/hip_runtime.h>
#include <hip/hip_bf16.h>

typedef __attribute__((ext_vector_type(8))) short bf16x8;
typedef __attribute__((ext_vector_type(4))) float f32x4;

#define NB 16384
#define NE 31

static __device__ __forceinline__ unsigned short f2b(float f) {
  unsigned int u = __builtin_bit_cast(unsigned int, f);
  return (unsigned short)((u + 0x7fffu + ((u >> 16) & 1u)) >> 16);
}
static __device__ __forceinline__ float b2f(unsigned short h) {
  return __builtin_bit_cast(float, ((unsigned int)h) << 16);
}
static __device__ __forceinline__ unsigned int cvtpk(float a, float b) {
  unsigned int r;
  asm("v_cvt_pk_bf16_f32 %0, %1, %2" : "=v"(r) : "v"(a), "v"(b));
  return r;
}
static __device__ __forceinline__ float lo16(unsigned int v) {
  return __builtin_bit_cast(float, v << 16);
}
static __device__ __forceinline__ float hi16(unsigned int v) {
  return __builtin_bit_cast(float, v & 0xffff0000u);
}

// ---------------------------------------------------------------------------
// k0_all: weight preprocessing (one launch).
// W1 (bf16 [1792][256]): rows 0..255 = 0.125*Wq; 256..511 = Wk; 512..767 = Wv;
//   rows 768..1791 = Wqo[h*256+c][k] = sum_d 0.125*Wq[h*64+d][k]*Wok[h*64+d][c]
// W2 (bf16 [256][1280]): row n: cols h*256+c = sum_d Wov[h*64+d][c]*Wc[n][h*64+d];
//   cols 1024+m = Wc[n][m]
// ---------------------------------------------------------------------------
__global__ void k0_all(const float* __restrict__ wq, const float* __restrict__ wk,
                       const float* __restrict__ wv, const float* __restrict__ wok,
                       const float* __restrict__ wov, const float* __restrict__ wc,
                       unsigned short* __restrict__ W1, unsigned short* __restrict__ W2) {
  int r = blockIdx.x, k = threadIdx.x;
  if (r < 1024) {
    if (r < 256) {
      W1[r * 256 + k] = f2b(0.125f * wq[r * 256 + k]);
    } else if (r < 512) {
      W1[r * 256 + k] = f2b(wk[(r - 256) * 256 + k]);
    } else if (r < 768) {
      W1[r * 256 + k] = f2b(wv[(r - 512) * 256 + k]);
    } else {
      int n = r - 768;
      W2[n * 1280 + 1024 + k] = f2b(wc[n * 256 + k]);
    }
  } else if (r < 2048) {
    int m = r - 1024;  // 0..1023
    int h = m >> 8, c = m & 255;
    float acc = 0.f;
#pragma unroll 8
    for (int d = 0; d < 64; ++d)
      acc = fmaf(wq[(h * 64 + d) * 256 + k], wok[(h * 64 + d) * 256 + c], acc);
    W1[(768 + m) * 256 + k] = f2b(0.125f * acc);
  } else {
    int n = r - 2048;  // 0..255
#pragma unroll 1
    for (int mi = 0; mi < 4; ++mi) {
      float acc = 0.f;
#pragma unroll 8
      for (int d = 0; d < 64; ++d)
        acc = fmaf(wov[(mi * 64 + d) * 256 + k], wc[n * 256 + mi * 64 + d], acc);
      W2[n * 1280 + mi * 256 + k] = f2b(acc);
    }
  }
}

// ---------------------------------------------------------------------------
// k1b: qkv2[b][n] = sum_k ego[b][k] * W1[n][k]. bf16 out.
// 512 blocks: (row-group 64) x (col-half 896); 2 blocks/CU.
// 4 waves x 224-col stripe (7 tiles of 32 cols).
// ---------------------------------------------------------------------------
__global__ __launch_bounds__(256, 2)
void k1b(const float* __restrict__ ego, const unsigned short* __restrict__ W1,
         unsigned short* __restrict__ qkv2) {
  __shared__ __align__(16) unsigned short Al[64 * 256];  // 32KB, swizzled
  const int tid = threadIdx.x;
  const int bM = (blockIdx.x >> 1) * 64;
  const int half = (blockIdx.x & 1) * 896;
#pragma unroll
  for (int it = 0; it < 8; ++it) {
    int c = tid + it * 256;                // 2048 chunks of 8 f32
    int row = c >> 5, k8 = c & 31;
    const float4* g = (const float4*)(ego + (size_t)(bM + row) * 256 + k8 * 8);
    float4 x = g[0], y = g[1];
    float t[8] = {x.x, x.y, x.z, x.w, y.x, y.y, y.z, y.w};
    bf16x8 v;
#pragma unroll
    for (int j = 0; j < 8; ++j) v[j] = (short)f2b(t[j]);
    int byteoff = row * 512 + ((k8 * 16) ^ ((row & 7) << 4));
    *(bf16x8*)((char*)Al + byteoff) = v;
  }
  __syncthreads();
  const int w = tid >> 6, lane = tid & 63, lr = lane & 15, lkg = lane >> 4;
#pragma unroll 1
  for (int cb = 0; cb < 7; ++cb) {
    int bN = half + w * 224 + cb * 32;
    f32x4 acc[4][2];
#pragma unroll
    for (int mt = 0; mt < 4; ++mt)
#pragma unroll
      for (int nt = 0; nt < 2; ++nt) acc[mt][nt] = (f32x4){0.f, 0.f, 0.f, 0.f};
#pragma unroll
    for (int kk = 0; kk < 8; ++kk) {
      int kidx = kk * 32 + lkg * 8;
      bf16x8 bfr[2];
#pragma unroll
      for (int nt = 0; nt < 2; ++nt)
        bfr[nt] = *(const bf16x8*)(W1 + (size_t)(bN + nt * 16 + lr) * 256 + kidx);
#pragma unroll
      for (int mt = 0; mt < 4; ++mt) {
        int row = mt * 16 + lr;
        int byteoff = row * 512 + ((kidx * 2) ^ ((row & 7) << 4));
        bf16x8 a = *(const bf16x8*)((const char*)Al + byteoff);
#pragma unroll
        for (int nt = 0; nt < 2; ++nt)
          acc[mt][nt] = __builtin_amdgcn_mfma_f32_16x16x32_bf16(a, bfr[nt], acc[mt][nt], 0, 0, 0);
      }
    }
#pragma unroll
    for (int mt = 0; mt < 4; ++mt)
#pragma unroll
      for (int nt = 0; nt < 2; ++nt)
#pragma unroll
        for (int j = 0; j < 4; ++j) {
          int row = bM + mt * 16 + lkg * 4 + j;
          int col = bN + nt * 16 + lr;
          qkv2[(size_t)row * 1792 + col] = f2b(acc[mt][nt][j]);
        }
  }
}

// ---------------------------------------------------------------------------
// ks_attn: ONE WAVE = ONE ITEM, zero barriers. 4 waves/block, private LDS
// slices. Stage X bf16 (swizzled LDS for MFMA + packed regs for ctx),
// MFMA scores, in-wave softmax, ctx from REGISTERS. grid = NB/4.
// ---------------------------------------------------------------------------
__global__ __launch_bounds__(256, 2)
void ks_attn(const float* __restrict__ others, const int* __restrict__ mask,
             const unsigned short* __restrict__ qkv2,
             unsigned short* __restrict__ u,
             float* __restrict__ attnout) {
  __shared__ __align__(16) unsigned short Xs[4][8192];  // 16KB per wave
  __shared__ __align__(16) float Ps[4][32][4];          // [key][head] per wave
  const int tid = threadIdx.x;
  const int w = tid >> 6, lane = tid & 63, lr = lane & 15, lkg = lane >> 4;
  const size_t b = (size_t)blockIdx.x * 4 + w;
  char* Xc = (char*)Xs[w];
  float (*P)[4] = Ps[w];
  const unsigned short* qk = qkv2 + b * 1792;

  // ---- preload A-fragments (Qo) + ego q/k/v bits (L2-resident) ----
  bf16x8 af[8];
#pragma unroll
  for (int kk = 0; kk < 8; ++kk)
    af[kk] = *(const bf16x8*)(qk + 768 + (lr & 3) * 256 + kk * 32 + lkg * 8);
  ushort4 qa = *(const ushort4*)(qk + lkg * 64 + lr * 4);
  ushort4 kb = *(const ushort4*)(qk + 256 + lkg * 64 + lr * 4);
  ushort4 ve = *(const ushort4*)(qk + 512 + lane * 4);
  int mk0 = mask[b * 32 + 1 + lr];
  int mk1 = (lr == 15) ? 1 : mask[b * 32 + 17 + lr];
  int mkE = mask[b * 32];

  // ---- stage X: row j, f32-chunk `lane` (coalesced 1KB/inst).
  //      Keep packed copy xv[j] in regs: lane owns cols 4*lane..4*lane+3. ----
  uint2 xv[NE];
  {
    const char* src = (const char*)(others + b * (NE * 256)) + lane * 16;
#pragma unroll
    for (int j = 0; j < NE; ++j) {
      float4 f = *(const float4*)(src + j * 1024);
      uint2 v;
      v.x = cvtpk(f.x, f.y);
      v.y = cvtpk(f.z, f.w);
      xv[j] = v;
      *(uint2*)(Xc + j * 512 + ((lane * 8) ^ ((j & 15) << 4))) = v;
    }
    uint2 z; z.x = 0; z.y = 0;
    *(uint2*)(Xc + 31 * 512 + ((lane * 8) ^ ((31 & 15) << 4))) = z;
  }

  // ---- s0[h] = q_h . k_ego_h (q pre-scaled); group lkg computes head lkg ----
  float s0p = b2f(qa.x) * b2f(kb.x) + b2f(qa.y) * b2f(kb.y) +
              b2f(qa.z) * b2f(kb.z) + b2f(qa.w) * b2f(kb.w);
#pragma unroll
  for (int off = 1; off < 16; off <<= 1) s0p += __shfl_xor(s0p, off, 16);
  float s0h[4];
  s0h[0] = __shfl(s0p, 0);
  s0h[1] = __shfl(s0p, 16);
  s0h[2] = __shfl(s0p, 32);
  s0h[3] = __shfl(s0p, 48);

  asm volatile("s_waitcnt lgkmcnt(0)" ::: "memory");
  __builtin_amdgcn_sched_barrier(0);

  // ---- scores: S[h][e] via MFMA; D row m=h (valid on lkg==0), col n=e ----
  f32x4 acc0 = (f32x4){0.f, 0.f, 0.f, 0.f};
  f32x4 acc1 = (f32x4){0.f, 0.f, 0.f, 0.f};
#pragma unroll
  for (int kk = 0; kk < 8; ++kk) {
    int co = kk * 64 + lkg * 16;
    bf16x8 b0 = *(const bf16x8*)(Xc + lr * 512 + (co ^ (lr << 4)));
    bf16x8 b1 = *(const bf16x8*)(Xc + (16 + lr) * 512 + (co ^ (lr << 4)));
    acc0 = __builtin_amdgcn_mfma_f32_16x16x32_bf16(af[kk], b0, acc0, 0, 0, 0);
    acc1 = __builtin_amdgcn_mfma_f32_16x16x32_bf16(af[kk], b1, acc1, 0, 0, 0);
  }

  // ---- masked softmax per head (width-16 shfl groups; lkg==0 valid) ----
  float pr0[4], pr1[4], p0v[4];
#pragma unroll
  for (int j = 0; j < 4; ++j) {
    float sj0 = mk0 ? -1e9f : acc0[j];
    float sj1 = mk1 ? -1e9f : acc1[j];
    float se  = mkE ? -1e9f : s0h[j];
    float mx = fmaxf(se, fmaxf(sj0, sj1));
#pragma unroll
    for (int off = 1; off < 16; off <<= 1) mx = fmaxf(mx, __shfl_xor(mx, off, 16));
    float e0 = __expf(sj0 - mx), e1 = __expf(sj1 - mx), ee = __expf(se - mx);
    float sm = e0 + e1;
#pragma unroll
    for (int off = 1; off < 16; off <<= 1) sm += __shfl_xor(sm, off, 16);
    float rinv = 1.f / (sm + ee);
    pr0[j] = e0 * rinv;
    pr1[j] = e1 * rinv;
    p0v[j] = ee * rinv;
  }
  if (lkg == 0) {
    float4 q0, q1;
    q0.x = pr0[0]; q0.y = pr0[1]; q0.z = pr0[2]; q0.w = pr0[3];
    *(float4*)&P[1 + lr][0] = q0;
    if (lr < 15) {
      q1.x = pr1[0]; q1.y = pr1[1]; q1.z = pr1[2]; q1.w = pr1[3];
      *(float4*)&P[17 + lr][0] = q1;
    }
    if (lr == 0) {
      float4 qe;
      qe.x = p0v[0]; qe.y = p0v[1]; qe.z = p0v[2]; qe.w = p0v[3];
      *(float4*)&P[0][0] = qe;
    }
#pragma unroll
    for (int j = 0; j < 4; ++j) {
      attnout[b * 128 + j * 32 + 1 + lr] = pr0[j];
      if (lr < 15) attnout[b * 128 + j * 32 + 17 + lr] = pr1[j];
      if (lr == 0) attnout[b * 128 + j * 32] = p0v[j];
    }
  }
  asm volatile("s_waitcnt lgkmcnt(0)" ::: "memory");
  __builtin_amdgcn_sched_barrier(0);

  // ---- ctx[h][d] = sum_e P[h][e] X[e][d]; lane owns 4 d-cols (from regs) ----
  f32x4 cx[4];
#pragma unroll
  for (int h = 0; h < 4; ++h) cx[h] = (f32x4){0.f, 0.f, 0.f, 0.f};
#pragma unroll
  for (int e = 0; e < NE; ++e) {
    float4 p = *(const float4*)&P[1 + e][0];
    uint2 v = xv[e];
    float x0 = lo16(v.x), x1 = hi16(v.x), x2 = lo16(v.y), x3 = hi16(v.y);
    cx[0][0] = fmaf(p.x, x0, cx[0][0]); cx[0][1] = fmaf(p.x, x1, cx[0][1]);
    cx[0][2] = fmaf(p.x, x2, cx[0][2]); cx[0][3] = fmaf(p.x, x3, cx[0][3]);
    cx[1][0] = fmaf(p.y, x0, cx[1][0]); cx[1][1] = fmaf(p.y, x1, cx[1][1]);
    cx[1][2] = fmaf(p.y, x2, cx[1][2]); cx[1][3] = fmaf(p.y, x3, cx[1][3]);
    cx[2][0] = fmaf(p.z, x0, cx[2][0]); cx[2][1] = fmaf(p.z, x1, cx[2][1]);
    cx[2][2] = fmaf(p.z, x2, cx[2][2]); cx[2][3] = fmaf(p.z, x3, cx[2][3]);
    cx[3][0] = fmaf(p.w, x0, cx[3][0]); cx[3][1] = fmaf(p.w, x1, cx[3][1]);
    cx[3][2] = fmaf(p.w, x2, cx[3][2]); cx[3][3] = fmaf(p.w, x3, cx[3][3]);
  }
#pragma unroll
  for (int h = 0; h < 4; ++h) {
    ushort4 st;
    st.x = f2b(cx[h][0]); st.y = f2b(cx[h][1]);
    st.z = f2b(cx[h][2]); st.w = f2b(cx[h][3]);
    *(ushort4*)(u + b * 1280 + h * 256 + lane * 4) = st;
  }
  // p0 * v_ego (head = lkg for this lane's 4-col slice)
  float p0h = P[0][lkg];
  ushort4 sv;
  sv.x = f2b(p0h * b2f(ve.x)); sv.y = f2b(p0h * b2f(ve.y));
  sv.z = f2b(p0h * b2f(ve.z)); sv.w = f2b(p0h * b2f(ve.w));
  *(ushort4*)(u + b * 1280 + 1024 + lane * 4) = sv;
}

// ---------------------------------------------------------------------------
// k4: res[b][n] = (sum_m u[b][m]*W2[n][m] + ego[b][n]) * 0.5
// 512 blocks x 32 rows; K looped in 5 chunks of 256; 4 waves = 64-col stripes.
// ---------------------------------------------------------------------------
__global__ __launch_bounds__(256, 2)
void k4_out(const unsigned short* __restrict__ u, const unsigned short* __restrict__ W2,
            const float* __restrict__ ego, float* __restrict__ out) {
  __shared__ __align__(16) unsigned short Au[32 * 256];  // 16KB, swizzled
  const int tid = threadIdx.x;
  const int bM = blockIdx.x * 32;
  const int w = tid >> 6, lane = tid & 63, lr = lane & 15, lkg = lane >> 4;
  f32x4 acc[2][4];
#pragma unroll
  for (int mt = 0; mt < 2; ++mt)
#pragma unroll
    for (int nt = 0; nt < 4; ++nt) acc[mt][nt] = (f32x4){0.f, 0.f, 0.f, 0.f};
#pragma unroll 1
  for (int kc = 0; kc < 5; ++kc) {
#pragma unroll
    for (int it = 0; it < 4; ++it) {
      int c = tid + it * 256;              // 1024 chunks of 8 bf16
      int row = c >> 5, k8 = c & 31;
      bf16x8 v = *(const bf16x8*)(u + (size_t)(bM + row) * 1280 + kc * 256 + k8 * 8);
      int byteoff = row * 512 + ((k8 * 16) ^ ((row & 7) << 4));
      *(bf16x8*)((char*)Au + byteoff) = v;
    }
    __syncthreads();
#pragma unroll
    for (int kk = 0; kk < 8; ++kk) {
      int kidx = kk * 32 + lkg * 8;
      bf16x8 bfr[4];
#pragma unroll
      for (int nt = 0; nt < 4; ++nt)
        bfr[nt] = *(const bf16x8*)(W2 + (size_t)(w * 64 + nt * 16 + lr) * 1280 + kc * 256 + kidx);
#pragma unroll
      for (int mt = 0; mt < 2; ++mt) {
        int row = mt * 16 + lr;
        int byteoff = row * 512 + ((kidx * 2) ^ ((row & 7) << 4));
        bf16x8 a = *(const bf16x8*)((const char*)Au + byteoff);
#pragma unroll
        for (int nt = 0; nt < 4; ++nt)
          acc[mt][nt] = __builtin_amdgcn_mfma_f32_16x16x32_bf16(a, bfr[nt], acc[mt][nt], 0, 0, 0);
      }
    }
    __syncthreads();
  }
#pragma unroll
  for (int mt = 0; mt < 2; ++mt)
#pragma unroll
    for (int nt = 0; nt < 4; ++nt)
#pragma unroll
      for (int j = 0; j < 4; ++j) {
        int row = bM + mt * 16 + lkg * 4 + j;
        int col = w * 64 + nt * 16 + lr;
        out[(size_t)row * 256 + col] = (acc[mt][nt][j] + ego[(size_t)row * 256 + col]) * 0.5f;
      }
}

extern "C" void kernel_launch(void* const* d_in, const int* in_sizes, int n_in,
                              void* d_out, int out_size, void* d_ws, size_t ws_size,
                              hipStream_t stream) {
  const float* ego    = (const float*)d_in[0];
  const float* others = (const float*)d_in[1];
  const int*   mask   = (const int*)d_in[2];
  const float* wq  = (const float*)d_in[3];
  const float* wk  = (const float*)d_in[4];
  const float* wv  = (const float*)d_in[5];
  const float* wok = (const float*)d_in[6];
  const float* wov = (const float*)d_in[7];
  const float* wc  = (const float*)d_in[8];

  unsigned short* W1   = (unsigned short*)d_ws;                 // 1792*256
  unsigned short* W2   = W1 + 1792 * 256;                       // 256*1280
  unsigned short* qkv2 = W2 + 256 * 1280;                       // NB*1792
  unsigned short* u    = qkv2 + (size_t)NB * 1792;              // NB*1280

  float* res  = (float*)d_out;                                  // NB*256 f32
  float* attn = res + (size_t)NB * 256;                         // NB*128 f32

  hipLaunchKernelGGL(k0_all, dim3(2304), dim3(256), 0, stream,
                     wq, wk, wv, wok, wov, wc, W1, W2);
  hipLaunchKernelGGL(k1b,    dim3(512),  dim3(256), 0, stream, ego, W1, qkv2);
  hipLaunchKernelGGL(ks_attn, dim3(NB / 4), dim3(256), 0, stream,
                     others, mask, qkv2, u, attn);
  hipLaunchKernelGGL(k4_out, dim3(512),  dim3(256), 0, stream, u, W2, ego, res);
}